// Round 26
// baseline (118.746 us; speedup 1.0000x reference)
//
#include <hip/hip_runtime.h>
#include <math.h>

#define BATCH 4
#define NSUP 25
#define NQ   75
#define CH   640
#define HW   100
#define NWAY 5
#define KSHOT 5
#define NSYS (BATCH*NQ)   // 300
#define MS   (NWAY*HW)    // 500
#define MQ   HW           // 100
#define MTOT (NQ*HW)      // 7500 rows per batch
#define NCHK 20           // c-chunks of 32

// chunk-major slab geometry (u16 units)
#define A_BSTRIDE 241664          // 7552*32 (59 slabs of 128 rows)
#define A_KSTRIDE 966656          // 4*A_BSTRIDE
#define B_BSTRIDE 16384           // 512*32  (4 slabs)
#define B_KSTRIDE 65536           // 4*B_BSTRIDE

typedef __attribute__((ext_vector_type(8))) _Float16 f16x8;
typedef __attribute__((ext_vector_type(8))) short bf16x8;
typedef __attribute__((ext_vector_type(4))) float f32x4;
typedef __attribute__((ext_vector_type(16))) float f32x16;
typedef __attribute__((ext_vector_type(4))) short s16x4;

__device__ __forceinline__ ushort f2bf(float f) {
    unsigned u = __float_as_uint(f);
    u += 0x7fff + ((u >> 16) & 1);          // RNE
    return (ushort)(u >> 16);
}
__device__ __forceinline__ ushort f2h(float f) {
    _Float16 h = (_Float16)f;               // v_cvt_f16_f32, RNE
    return __builtin_bit_cast(unsigned short, h);
}

#define GLD_LDS16(gp, lp) __builtin_amdgcn_global_load_lds( \
    (const __attribute__((address_space(1))) unsigned*)(const void*)(gp), \
    (__attribute__((address_space(3))) unsigned*)(void*)(lp), 16, 0, 0)

// ---------------- K1: transpose + fp16 quantize -> chunk-major pre-swizzled slabs ----------------
__global__ __launch_bounds__(256) void k_prep_all(
        const float* __restrict__ qry, const float* __restrict__ sup,
        ushort* __restrict__ AhT, ushort* __restrict__ BhT,
        float* __restrict__ npq, float* __restrict__ nps) {
    __shared__ float tile[32][101];
    int kt = blockIdx.x;
    int c0 = kt * 32;
    int z  = blockIdx.y;
    int t  = threadIdx.x;
    bool isq = (z < BATCH*NQ);

    ushort* dst; float* normpart; int planesHW; size_t cbase; int brow; int p;
    if (isq) {
        p = z;
        int b = p / NQ, qq = p % NQ;
        dst = AhT; normpart = npq; planesHW = NSYS*HW;
        cbase = (size_t)kt*A_KSTRIDE + (size_t)b*A_BSTRIDE;
        brow = qq*100;
        const float* ib = qry + (size_t)p*CH*HW + (size_t)c0*HW;
#pragma unroll
        for (int ii = 0; ii < 4; ++ii) {
            int idx = ii*256 + t;
            if (idx < 800) {
                int cl = idx / 25, qd = idx % 25;
                float4 v = *(const float4*)(ib + idx*4);
                tile[cl][qd*4+0] = v.x; tile[cl][qd*4+1] = v.y;
                tile[cl][qd*4+2] = v.z; tile[cl][qd*4+3] = v.w;
            }
        }
    } else {
        p = z - BATCH*NQ;
        int b = p / NWAY, n = p % NWAY;
        dst = BhT; normpart = nps; planesHW = BATCH*NWAY*HW;
        cbase = (size_t)kt*B_KSTRIDE + (size_t)b*B_BSTRIDE;
        brow = n*100;
        const float* ib = sup + ((size_t)(b*NSUP + n*KSHOT))*CH*HW + (size_t)c0*HW;
#pragma unroll
        for (int ii = 0; ii < 4; ++ii) {
            int idx = ii*256 + t;
            if (idx < 800) {
                float4 a = {0.f,0.f,0.f,0.f};
#pragma unroll
                for (int k = 0; k < KSHOT; ++k) {
                    float4 w = *(const float4*)(ib + (size_t)k*CH*HW + idx*4);
                    a.x += w.x; a.y += w.y; a.z += w.z; a.w += w.w;
                }
                int cl = idx / 25, qd = idx % 25;
                tile[cl][qd*4+0] = a.x*0.2f; tile[cl][qd*4+1] = a.y*0.2f;
                tile[cl][qd*4+2] = a.z*0.2f; tile[cl][qd*4+3] = a.w*0.2f;
            }
        }
    }
    __syncthreads();
#pragma unroll
    for (int ii = 0; ii < 2; ++ii) {
        int idx = ii*256 + t;
        if (idx < 400) {
            int m  = idx >> 2;
            int sp = idx & 3;
            int rib = brow + m;
            int rl = rib & 127;
            int slab = rib >> 7;
            int cb = ((sp ^ ((rl >> 1) & 3))) << 3;
            bf16x8 o; float ss = 0.f;
#pragma unroll
            for (int j = 0; j < 8; ++j) {
                float f = tile[cb+j][m];
                ss += f*f;
                o[j] = (short)f2h(f);
            }
            size_t off = cbase + (size_t)slab*4096
                       + (size_t)((rl>>1)*64 + (rl&1)*32 + sp*8);
            *(bf16x8*)(dst + off) = o;
            ss += __shfl_xor(ss, 1);
            ss += __shfl_xor(ss, 2);
            if ((t & 3) == 0)
                normpart[(size_t)kt*planesHW + p*HW + m] = ss;
        }
    }
}

// ---------------- K2: fp16 MFMA GEMM + fused colsum partials (store-then-sum epilogue) ----------------
#define BM 128
#define BN 128
#define BK 64
#define NKT (CH/BK)           // 10
#define NCT 4
#define NRT 59
#define NWG (NCT*NRT*BATCH)   // 944, divisible by 8
__global__ __launch_bounds__(256) void k_gemm(
        const ushort* __restrict__ AhT, const ushort* __restrict__ BhT,
        const float* __restrict__ npq, const float* __restrict__ nps,
        float* __restrict__ S, float* __restrict__ pcs) {
    __shared__ __align__(1024) char lds[65536];   // 2 x 32KB
    __shared__ float invqL[128], invsL[128];
    __shared__ float csL[384];                    // [3 seg][128 col] colsum partials
    int hwid = blockIdx.x;
    int l = (hwid & 7) * (NWG/8) + (hwid >> 3);   // chunked XCD swizzle
    int ct = l & 3;
    int rest = l >> 2;
    int rt = rest % NRT;
    int b  = rest / NRT;
    int t  = threadIdx.x;
    int lane = t & 63, w = t >> 6;
    int row0 = rt * BM, col0 = ct * BN;

    if (t < 128) {
        int gr = row0 + t; if (gr > MTOT-1) gr = MTOT-1;
        float s = 0.f;
#pragma unroll
        for (int u = 0; u < NCHK; ++u) s += npq[(size_t)u*(NSYS*HW) + b*MTOT + gr];
        invqL[t] = 1.0f / (1e-16f + sqrtf(s));
    } else {
        int c = col0 + (t - 128); if (c > MS-1) c = MS-1;
        float s = 0.f;
#pragma unroll
        for (int u = 0; u < NCHK; ++u) s += nps[(size_t)u*(BATCH*NWAY*HW) + b*MS + c];
        invsL[t-128] = 1.0f / (1e-16f + sqrtf(s));
    }
    if (t < 128) csL[256 + t] = 0.f;
    csL[t] = 0.f;

    const ushort* srcA = AhT + (size_t)b*A_BSTRIDE + (size_t)rt*4096;
    const ushort* srcB = BhT + (size_t)b*B_BSTRIDE + (size_t)ct*4096;
    int dA = w << 10;

    f32x4 acc[4][4];
#pragma unroll
    for (int mi = 0; mi < 4; ++mi)
#pragma unroll
        for (int ni = 0; ni < 4; ++ni) acc[mi][ni] = (f32x4){0.f,0.f,0.f,0.f};

    int wr = w >> 1, wc = w & 1;
    int q = lane & 15, kg = lane >> 4;

#define STAGE(bufb, kt_) do { \
        const ushort* pa0 = srcA + (size_t)(2*(kt_))*A_KSTRIDE; \
        const ushort* pa1 = pa0 + A_KSTRIDE; \
        const ushort* pb0 = srcB + (size_t)(2*(kt_))*B_KSTRIDE; \
        const ushort* pb1 = pb0 + B_KSTRIDE; \
        char* bb = lds + (bufb)*32768; \
        GLD_LDS16(pa0 + t*8,        bb + 0     + dA); \
        GLD_LDS16(pa0 + 2048 + t*8, bb + 4096  + dA); \
        GLD_LDS16(pa1 + t*8,        bb + 8192  + dA); \
        GLD_LDS16(pa1 + 2048 + t*8, bb + 12288 + dA); \
        GLD_LDS16(pb0 + t*8,        bb + 16384 + dA); \
        GLD_LDS16(pb0 + 2048 + t*8, bb + 20480 + dA); \
        GLD_LDS16(pb1 + t*8,        bb + 24576 + dA); \
        GLD_LDS16(pb1 + 2048 + t*8, bb + 28672 + dA); \
    } while (0)

    STAGE(0, 0);
    for (int kt = 0; kt < NKT; ++kt) {
        int cur = kt & 1;
        if (kt + 1 < NKT) {
            STAGE(cur ^ 1, kt + 1);
            asm volatile("s_waitcnt vmcnt(8)" ::: "memory");
        } else {
            asm volatile("s_waitcnt vmcnt(0)" ::: "memory");
        }
        __builtin_amdgcn_sched_barrier(0);
        __builtin_amdgcn_s_barrier();
        __builtin_amdgcn_sched_barrier(0);

        const char* buf = lds + cur*32768;
#pragma unroll
        for (int h = 0; h < 2; ++h) {
            const char* Ab = buf + h*8192;
            const char* Bb = buf + 16384 + h*8192;
            f16x8 bf[4];
#pragma unroll
            for (int ni = 0; ni < 4; ++ni) {
                int c = wc*64 + ni*16 + q;
                int off = (c>>1)*128 + (c&1)*64 + ((kg ^ ((c>>1)&3)) << 4);
                bf[ni] = *(const f16x8*)(Bb + off);
            }
#pragma unroll
            for (int mi = 0; mi < 4; ++mi) {
                int r = wr*64 + mi*16 + q;
                int off = (r>>1)*128 + (r&1)*64 + ((kg ^ ((r>>1)&3)) << 4);
                f16x8 af = *(const f16x8*)(Ab + off);
#pragma unroll
                for (int ni = 0; ni < 4; ++ni)
                    acc[mi][ni] = __builtin_amdgcn_mfma_f32_16x16x32_f16(af, bf[ni], acc[mi][ni], 0, 0, 0);
            }
        }
        __builtin_amdgcn_sched_barrier(0);
        __builtin_amdgcn_s_barrier();
        __builtin_amdgcn_sched_barrier(0);
    }
#undef STAGE

    int colb = col0 + wc*64 + q;
    int rowb = row0 + wr*64 + (kg << 2);
    // pass 1: S stores in the R24 order (mi outer, ni inner) -> complete 256B lines fast
#pragma unroll
    for (int mi = 0; mi < 4; ++mi) {
#pragma unroll
        for (int ni = 0; ni < 4; ++ni) {
            int c = colb + ni*16;
            if (c >= MS) continue;
            float si = invsL[c - col0];
#pragma unroll
            for (int j = 0; j < 4; ++j) {
                int r = rowb + mi*16 + j;
                if (r < MTOT)
                    S[((size_t)b*MTOT + r)*MS + c] = acc[mi][ni][j] * invqL[r - row0] * si;
            }
        }
    }
    // pass 2: colsum partials from registers (recompute v; no global traffic)
    {
        int sys0 = row0 / 100;
        int segb = rowb / 100 - sys0;                 // 0 or 1
        int rowcross = (rowb/100 + 1) * 100;
#pragma unroll
        for (int ni = 0; ni < 4; ++ni) {
            int c = colb + ni*16;
            if (c >= MS) continue;
            float si = invsL[c - col0];
            float s0 = 0.f, s1 = 0.f;
#pragma unroll
            for (int mi = 0; mi < 4; ++mi) {
#pragma unroll
                for (int j = 0; j < 4; ++j) {
                    int r = rowb + mi*16 + j;
                    if (r < MTOT) {
                        float v = acc[mi][ni][j] * invqL[r - row0] * si;
                        float e = __expf(10.f*(v - 1.0f));
                        if (r < rowcross) s0 += e; else s1 += e;
                    }
                }
            }
            atomicAdd(&csL[segb*128 + (c - col0)], s0);
            if (s1 != 0.f) atomicAdd(&csL[(segb+1)*128 + (c - col0)], s1);
        }
    }
    __syncthreads();
    for (int z = t; z < 384; z += 256) {
        int seg = z >> 7, cl = z & 127;
        int c = col0 + cl;
        if (c < MS)
            pcs[((size_t)(b*NRT + rt)*3 + seg)*512 + c] = csL[z];
    }
}

// ---------------- K3: fused MFMA formB + Jacobi; colsum gathered from gemm partials ----------------
__global__ __launch_bounds__(512) void k_fsolve(const float* __restrict__ S,
        const float* __restrict__ pcs, float* __restrict__ out) {
    __shared__ __align__(16) char PQ[65536];        // PT,QT / Bsh alias
    __shared__ __align__(16) float r10s[MS];
    __shared__ float r20L[MQ];
    __shared__ float xs[MQ], ys[MQ], rh[MQ];
    __shared__ float ps[4][MQ];
    __shared__ float partial[2];
    int sys = blockIdx.x;
    int t = threadIdx.x;
    int l = t & 63, w = t >> 6;
    const float* Sb = S + (size_t)sys*MQ*MS;
    char* PT = PQ;
    char* QT = PQ + 32768;

    // ---- phase A: gather colsum partials (1-2 loads per column) ----
    {
        int bq = sys / NQ, qq = sys % NQ;
        int rt1 = (qq*100) >> 7;
        int rt2 = (qq*100 + 99) >> 7;
        int seg1 = qq - (rt1*128)/100;
        const float* p1 = pcs + ((size_t)(bq*NRT + rt1)*3 + seg1)*512;
        const float* p2 = nullptr;
        if (rt2 != rt1) {
            int seg2 = qq - (rt2*128)/100;
            p2 = pcs + ((size_t)(bq*NRT + rt2)*3 + seg2)*512;
        }
        for (int c = t; c < MS; c += 512) {
            float s = p1[c];
            if (p2) s += p2[c];
            r10s[c] = 1.0f/s;
        }
        // barrier provided by first ck-iteration's __syncthreads()
    }

    int i = t >> 2;                  // 0..127, row per 4 threads
    int ccb = (t & 3) * 32;          // 32-col slice

    f32x16 acc[2];
#pragma unroll
    for (int nt = 0; nt < 2; ++nt)
#pragma unroll
        for (int rg = 0; rg < 16; ++rg) acc[nt][rg] = 0.f;

    int rw = w & 3, ch = w >> 2;
    int grA = rw*32 + (l & 31);
    int kg = l >> 5;
    const float* sr = Sb + (size_t)i*MS;

    for (int ck = 0; ck < 4; ++ck) {
        int c0 = ck*128;
        __syncthreads();
        if (i < MQ) {
#pragma unroll
            for (int j = 0; j < 8; ++j) {
                int cc = ccb + 4*j;
                int cg = c0 + cc;
                int phys = i*256 + ((((cc>>3) ^ (i&15)))<<4) + ((cc&7)*2);
                s16x4 pv, qv;
                if (cg < MS) {
                    float4 v  = *(const float4*)(sr + cg);
                    float4 r1 = *(const float4*)&r10s[cg];
                    pv.x = (short)f2bf(__expf(10.f*(v.x - 1.0f))*r1.x);
                    pv.y = (short)f2bf(__expf(10.f*(v.y - 1.0f))*r1.y);
                    pv.z = (short)f2bf(__expf(10.f*(v.z - 1.0f))*r1.z);
                    pv.w = (short)f2bf(__expf(10.f*(v.w - 1.0f))*r1.w);
                    qv.x = (short)f2bf(__expf(20.f*(v.x - 1.0f)));
                    qv.y = (short)f2bf(__expf(20.f*(v.y - 1.0f)));
                    qv.z = (short)f2bf(__expf(20.f*(v.z - 1.0f)));
                    qv.w = (short)f2bf(__expf(20.f*(v.w - 1.0f)));
                } else {
                    pv = (s16x4){0,0,0,0}; qv = (s16x4){0,0,0,0};
                }
                *(s16x4*)(PT + phys) = pv;
                *(s16x4*)(QT + phys) = qv;
            }
        } else {
            short one = (short)0x3F80;
#pragma unroll
            for (int j = 0; j < 8; ++j) {
                int cc = ccb + 4*j;
                int cg = c0 + cc;
                int phys = i*256 + ((((cc>>3) ^ (i&15)))<<4) + ((cc&7)*2);
                s16x4 z = (s16x4){0,0,0,0};
                s16x4 ov = z;
                if (i == MQ && cg < MS) ov = (s16x4){one, one, one, one};
                *(s16x4*)(PT + phys) = ov;   // ones-row in P' -> row 100 of B = rowsum(Q_un)
                *(s16x4*)(QT + phys) = ov;   // ones-row in Q  -> col 100 of B = rhs sums
            }
        }
        __syncthreads();
#pragma unroll
        for (int kk = 0; kk < 8; ++kk) {
            int sA = (kk*2 + kg) ^ (grA & 15);
            bf16x8 af = *(const bf16x8*)(PT + grA*256 + (sA<<4));
#pragma unroll
            for (int nt = 0; nt < 2; ++nt) {
                int gc = (ch*2 + nt)*32 + (l & 31);
                int sB = (kk*2 + kg) ^ (gc & 15);
                bf16x8 bfr = *(const bf16x8*)(QT + gc*256 + (sB<<4));
                acc[nt] = __builtin_amdgcn_mfma_f32_32x32x16_bf16(af, bfr, acc[nt], 0, 0, 0);
            }
        }
    }
    __syncthreads();

    float* Bsh = (float*)PQ;          // [101][101] un-normalized B
#pragma unroll
    for (int nt = 0; nt < 2; ++nt) {
        int col = (ch*2 + nt)*32 + (l & 31);
        if (col > MQ) continue;
#pragma unroll
        for (int rg = 0; rg < 16; ++rg) {
            int row = rw*32 + (rg & 3) + 8*(rg >> 2) + 4*(l >> 5);
            if (row <= MQ) Bsh[row*101 + col] = acc[nt][rg];
        }
    }
    __syncthreads();
    if (t < MQ) {
        float r20 = 1.0f / Bsh[100*101 + t];
        r20L[t] = r20;
        float r = 1.0f + 0.5f*Bsh[t*101 + 100];
        rh[t] = r;
        xs[t] = r;
        ys[t] = r20 * r;
    }
    __syncthreads();
    int jr = t % MQ, jp = t / MQ;     // t<400: (row, part)
    for (int it = 0; it < 12; ++it) {
        if (t < 4*MQ) {
            float s = 0.f;
            const float* br = &Bsh[jr*101 + jp*25];
            const float* yv = &ys[jp*25];
#pragma unroll
            for (int j = 0; j < 25; ++j) s += br[j]*yv[j];
            ps[jp][jr] = s;
        }
        __syncthreads();
        if (t < MQ) {
            float x = rh[t] + 0.25f*(ps[0][t] + ps[1][t] + ps[2][t] + ps[3][t]);
            xs[t] = x;
            ys[t] = r20L[t] * x;
        }
        __syncthreads();
    }
    float kv = (t < MQ) ? (xs[t] - 1.0f) : 0.f;
    if (t < 128) {
        float s = kv;
        for (int off = 32; off; off >>= 1) s += __shfl_xor(s, off);
        if ((t & 63) == 0) partial[t >> 6] = s;
    }
    __syncthreads();
    float tot = partial[0] + partial[1];
    if (t < MQ) out[sys*MQ + t] = kv / tot;
}

extern "C" void kernel_launch(void* const* d_in, const int* in_sizes, int n_in,
                              void* d_out, int out_size, void* d_ws, size_t ws_size,
                              hipStream_t stream) {
    const float* sup = (const float*)d_in[0];
    const float* qry = (const float*)d_in[1];
    float* out = (float*)d_out;
    float* ws  = (float*)d_ws;

    float* supmean = ws;                        // 1,280,000 f (layout keeper)
    float* invs    = supmean + 1280000;         // 2,000 (unused)
    float* invq    = invs + 2000;               // 30,000 (unused)
    float* Smat    = invq + 30000;              // 15,000,000
    float* m20     = Smat + 15000000;           // 30,000 (unused)
    float* rd20    = m20 + 30000;               // 30,000 (unused)
    float* m10     = rd20 + 30000;              // 150,000 (unused)
    float* rd10    = m10 + 150000;              // 150,000 (unused)
    float* Bm      = rd10 + 150000;             // 3,000,000
    float* rh      = Bm + 3000000;              // 30,000 (unused)
    ushort* AhT    = (ushort*)(rh + 30000);     // 20*966,656 = 19,333,120 u16
    ushort* BhT    = AhT + 19333120;            // 20*65,536 = 1,310,720 u16
    float* npq     = Bm;                        // 20 x 30000 = 600,000
    float* nps     = Bm + 600000;               // 20 x 2000  = 40,000
    float* pcs     = Bm + 640000;               // 4*59*3*512 = 362,496 f

    k_prep_all<<<dim3(NCHK, BATCH*NQ + BATCH*NWAY), 256, 0, stream>>>(
        qry, sup, AhT, BhT, npq, nps);
    k_gemm<<<NWG, 256, 0, stream>>>(AhT, BhT, npq, nps, Smat, pcs);
    k_fsolve<<<NSYS, 512, 0, stream>>>(Smat, pcs, out);
}

// Round 27
// 110.359 us; speedup vs baseline: 1.0760x; 1.0760x over previous
//
#include <hip/hip_runtime.h>
#include <math.h>

#define BATCH 4
#define NSUP 25
#define NQ   75
#define CH   640
#define HW   100
#define NWAY 5
#define KSHOT 5
#define NSYS (BATCH*NQ)   // 300
#define MS   (NWAY*HW)    // 500
#define MQ   HW           // 100
#define MTOT (NQ*HW)      // 7500 rows per batch
#define NCHK 20           // c-chunks of 32

// chunk-major slab geometry (u16 units)
#define A_BSTRIDE 241664          // 7552*32 (59 slabs of 128 rows)
#define A_KSTRIDE 966656          // 4*A_BSTRIDE
#define B_BSTRIDE 16384           // 512*32  (4 slabs)
#define B_KSTRIDE 65536           // 4*B_BSTRIDE

typedef __attribute__((ext_vector_type(8))) _Float16 f16x8;
typedef __attribute__((ext_vector_type(8))) short bf16x8;
typedef __attribute__((ext_vector_type(4))) float f32x4;
typedef __attribute__((ext_vector_type(16))) float f32x16;
typedef __attribute__((ext_vector_type(4))) short s16x4;

__device__ __forceinline__ ushort f2bf(float f) {
    unsigned u = __float_as_uint(f);
    u += 0x7fff + ((u >> 16) & 1);          // RNE
    return (ushort)(u >> 16);
}
__device__ __forceinline__ ushort f2h(float f) {
    _Float16 h = (_Float16)f;               // v_cvt_f16_f32, RNE
    return __builtin_bit_cast(unsigned short, h);
}

#define GLD_LDS16(gp, lp) __builtin_amdgcn_global_load_lds( \
    (const __attribute__((address_space(1))) unsigned*)(const void*)(gp), \
    (__attribute__((address_space(3))) unsigned*)(void*)(lp), 16, 0, 0)

// ---------------- K1: transpose + fp16 quantize -> chunk-major pre-swizzled slabs ----------------
__global__ __launch_bounds__(256) void k_prep_all(
        const float* __restrict__ qry, const float* __restrict__ sup,
        ushort* __restrict__ AhT, ushort* __restrict__ BhT,
        float* __restrict__ npq, float* __restrict__ nps) {
    __shared__ float tile[32][101];
    int kt = blockIdx.x;
    int c0 = kt * 32;
    int z  = blockIdx.y;
    int t  = threadIdx.x;
    bool isq = (z < BATCH*NQ);

    ushort* dst; float* normpart; int planesHW; size_t cbase; int brow; int p;
    if (isq) {
        p = z;
        int b = p / NQ, qq = p % NQ;
        dst = AhT; normpart = npq; planesHW = NSYS*HW;
        cbase = (size_t)kt*A_KSTRIDE + (size_t)b*A_BSTRIDE;
        brow = qq*100;
        const float* ib = qry + (size_t)p*CH*HW + (size_t)c0*HW;
#pragma unroll
        for (int ii = 0; ii < 4; ++ii) {
            int idx = ii*256 + t;
            if (idx < 800) {
                int cl = idx / 25, qd = idx % 25;
                float4 v = *(const float4*)(ib + idx*4);
                tile[cl][qd*4+0] = v.x; tile[cl][qd*4+1] = v.y;
                tile[cl][qd*4+2] = v.z; tile[cl][qd*4+3] = v.w;
            }
        }
    } else {
        p = z - BATCH*NQ;
        int b = p / NWAY, n = p % NWAY;
        dst = BhT; normpart = nps; planesHW = BATCH*NWAY*HW;
        cbase = (size_t)kt*B_KSTRIDE + (size_t)b*B_BSTRIDE;
        brow = n*100;
        const float* ib = sup + ((size_t)(b*NSUP + n*KSHOT))*CH*HW + (size_t)c0*HW;
#pragma unroll
        for (int ii = 0; ii < 4; ++ii) {
            int idx = ii*256 + t;
            if (idx < 800) {
                float4 a = {0.f,0.f,0.f,0.f};
#pragma unroll
                for (int k = 0; k < KSHOT; ++k) {
                    float4 w = *(const float4*)(ib + (size_t)k*CH*HW + idx*4);
                    a.x += w.x; a.y += w.y; a.z += w.z; a.w += w.w;
                }
                int cl = idx / 25, qd = idx % 25;
                tile[cl][qd*4+0] = a.x*0.2f; tile[cl][qd*4+1] = a.y*0.2f;
                tile[cl][qd*4+2] = a.z*0.2f; tile[cl][qd*4+3] = a.w*0.2f;
            }
        }
    }
    __syncthreads();
#pragma unroll
    for (int ii = 0; ii < 2; ++ii) {
        int idx = ii*256 + t;
        if (idx < 400) {
            int m  = idx >> 2;
            int sp = idx & 3;
            int rib = brow + m;
            int rl = rib & 127;
            int slab = rib >> 7;
            int cb = ((sp ^ ((rl >> 1) & 3))) << 3;
            bf16x8 o; float ss = 0.f;
#pragma unroll
            for (int j = 0; j < 8; ++j) {
                float f = tile[cb+j][m];
                ss += f*f;
                o[j] = (short)f2h(f);
            }
            size_t off = cbase + (size_t)slab*4096
                       + (size_t)((rl>>1)*64 + (rl&1)*32 + sp*8);
            *(bf16x8*)(dst + off) = o;
            ss += __shfl_xor(ss, 1);
            ss += __shfl_xor(ss, 2);
            if ((t & 3) == 0)
                normpart[(size_t)kt*planesHW + p*HW + m] = ss;
        }
    }
}

// ---------------- K2: fp16 MFMA GEMM, BK=64 double-buffer + counted vmcnt ----------------
#define BM 128
#define BN 128
#define BK 64
#define NKT (CH/BK)           // 10
#define NCT 4
#define NRT 59
#define NWG (NCT*NRT*BATCH)   // 944, divisible by 8
__global__ __launch_bounds__(256) void k_gemm(
        const ushort* __restrict__ AhT, const ushort* __restrict__ BhT,
        const float* __restrict__ npq, const float* __restrict__ nps,
        float* __restrict__ S) {
    __shared__ __align__(1024) char lds[65536];   // 2 x 32KB
    __shared__ float invqL[128], invsL[128];
    int hwid = blockIdx.x;
    int l = (hwid & 7) * (NWG/8) + (hwid >> 3);   // chunked XCD swizzle
    int ct = l & 3;
    int rest = l >> 2;
    int rt = rest % NRT;
    int b  = rest / NRT;
    int t  = threadIdx.x;
    int lane = t & 63, w = t >> 6;
    int row0 = rt * BM, col0 = ct * BN;

    if (t < 128) {
        int gr = row0 + t; if (gr > MTOT-1) gr = MTOT-1;
        float s = 0.f;
#pragma unroll
        for (int u = 0; u < NCHK; ++u) s += npq[(size_t)u*(NSYS*HW) + b*MTOT + gr];
        invqL[t] = 1.0f / (1e-16f + sqrtf(s));
    } else {
        int c = col0 + (t - 128); if (c > MS-1) c = MS-1;
        float s = 0.f;
#pragma unroll
        for (int u = 0; u < NCHK; ++u) s += nps[(size_t)u*(BATCH*NWAY*HW) + b*MS + c];
        invsL[t-128] = 1.0f / (1e-16f + sqrtf(s));
    }

    const ushort* srcA = AhT + (size_t)b*A_BSTRIDE + (size_t)rt*4096;
    const ushort* srcB = BhT + (size_t)b*B_BSTRIDE + (size_t)ct*4096;
    int dA = w << 10;

    f32x4 acc[4][4];
#pragma unroll
    for (int mi = 0; mi < 4; ++mi)
#pragma unroll
        for (int ni = 0; ni < 4; ++ni) acc[mi][ni] = (f32x4){0.f,0.f,0.f,0.f};

    int wr = w >> 1, wc = w & 1;
    int q = lane & 15, kg = lane >> 4;

#define STAGE(bufb, kt_) do { \
        const ushort* pa0 = srcA + (size_t)(2*(kt_))*A_KSTRIDE; \
        const ushort* pa1 = pa0 + A_KSTRIDE; \
        const ushort* pb0 = srcB + (size_t)(2*(kt_))*B_KSTRIDE; \
        const ushort* pb1 = pb0 + B_KSTRIDE; \
        char* bb = lds + (bufb)*32768; \
        GLD_LDS16(pa0 + t*8,        bb + 0     + dA); \
        GLD_LDS16(pa0 + 2048 + t*8, bb + 4096  + dA); \
        GLD_LDS16(pa1 + t*8,        bb + 8192  + dA); \
        GLD_LDS16(pa1 + 2048 + t*8, bb + 12288 + dA); \
        GLD_LDS16(pb0 + t*8,        bb + 16384 + dA); \
        GLD_LDS16(pb0 + 2048 + t*8, bb + 20480 + dA); \
        GLD_LDS16(pb1 + t*8,        bb + 24576 + dA); \
        GLD_LDS16(pb1 + 2048 + t*8, bb + 28672 + dA); \
    } while (0)

    STAGE(0, 0);
    for (int kt = 0; kt < NKT; ++kt) {
        int cur = kt & 1;
        if (kt + 1 < NKT) {
            STAGE(cur ^ 1, kt + 1);
            asm volatile("s_waitcnt vmcnt(8)" ::: "memory");
        } else {
            asm volatile("s_waitcnt vmcnt(0)" ::: "memory");
        }
        __builtin_amdgcn_sched_barrier(0);
        __builtin_amdgcn_s_barrier();
        __builtin_amdgcn_sched_barrier(0);

        const char* buf = lds + cur*32768;
#pragma unroll
        for (int h = 0; h < 2; ++h) {
            const char* Ab = buf + h*8192;
            const char* Bb = buf + 16384 + h*8192;
            f16x8 bf[4];
#pragma unroll
            for (int ni = 0; ni < 4; ++ni) {
                int c = wc*64 + ni*16 + q;
                int off = (c>>1)*128 + (c&1)*64 + ((kg ^ ((c>>1)&3)) << 4);
                bf[ni] = *(const f16x8*)(Bb + off);
            }
#pragma unroll
            for (int mi = 0; mi < 4; ++mi) {
                int r = wr*64 + mi*16 + q;
                int off = (r>>1)*128 + (r&1)*64 + ((kg ^ ((r>>1)&3)) << 4);
                f16x8 af = *(const f16x8*)(Ab + off);
#pragma unroll
                for (int ni = 0; ni < 4; ++ni)
                    acc[mi][ni] = __builtin_amdgcn_mfma_f32_16x16x32_f16(af, bf[ni], acc[mi][ni], 0, 0, 0);
            }
        }
        __builtin_amdgcn_sched_barrier(0);
        __builtin_amdgcn_s_barrier();
        __builtin_amdgcn_sched_barrier(0);
    }
#undef STAGE

    int colb = col0 + wc*64 + q;
    int rowb = row0 + wr*64 + (kg << 2);
#pragma unroll
    for (int mi = 0; mi < 4; ++mi) {
#pragma unroll
        for (int ni = 0; ni < 4; ++ni) {
            int c = colb + ni*16;
            if (c >= MS) continue;
            float si = invsL[c - col0];
#pragma unroll
            for (int j = 0; j < 4; ++j) {
                int r = rowb + mi*16 + j;
                if (r < MTOT)
                    S[((size_t)b*MTOT + r)*MS + c] = acc[mi][ni][j] * invqL[r - row0] * si;
            }
        }
    }
}

// ---------------- K3: fused colsum + MFMA formB + Jacobi, max-free softmax ----------------
__global__ __launch_bounds__(512) void k_fsolve(const float* __restrict__ S,
        float* __restrict__ out) {
    __shared__ __align__(16) char PQ[65536];        // phaseA tmp / PT,QT / Bsh alias
    __shared__ __align__(16) float r10s[MS];
    __shared__ float r20L[MQ];
    __shared__ float xs[MQ], ys[MQ], rh[MQ];
    __shared__ float ps[4][MQ];
    __shared__ float partial[2];
    int sys = blockIdx.x;
    int t = threadIdx.x;
    int l = t & 63, w = t >> 6;
    const float* Sb = S + (size_t)sys*MQ*MS;
    char* PT = PQ;
    char* QT = PQ + 32768;

    // ---- phase A: colsum_c = sum_i exp(10*(S[i][c]-1)) ; r10 = 1/colsum ----
    {
        float (*wcs)[512] = (float(*)[512])PQ;            // [8][512] partials
        float cols[8];
#pragma unroll
        for (int u = 0; u < 8; ++u) cols[u] = 0.f;
        int nu = (l < MS - 448) ? 8 : 7;   // l<52 -> 8 cols
        for (int row = w; row < MQ; row += 8) {
            const float* rp = Sb + (size_t)row*MS;
#pragma unroll
            for (int u = 0; u < 8; ++u)
                if (u < nu) cols[u] += __expf(10.f*(rp[l + 64*u] - 1.0f));
        }
#pragma unroll
        for (int u = 0; u < 8; ++u) wcs[w][l+64*u] = cols[u];
        __syncthreads();
        if (t < MS) {
            float s = 0.f;
#pragma unroll
            for (int w2 = 0; w2 < 8; ++w2) s += wcs[w2][t];
            r10s[t] = 1.0f/s;
        }
        // barrier provided by first ck-iteration's __syncthreads()
    }

    int i = t >> 2;                  // 0..127, row per 4 threads
    int ccb = (t & 3) * 32;          // 32-col slice

    f32x16 acc[2];
#pragma unroll
    for (int nt = 0; nt < 2; ++nt)
#pragma unroll
        for (int rg = 0; rg < 16; ++rg) acc[nt][rg] = 0.f;

    int rw = w & 3, ch = w >> 2;
    int grA = rw*32 + (l & 31);
    int kg = l >> 5;
    const float* sr = Sb + (size_t)i*MS;

    for (int ck = 0; ck < 4; ++ck) {
        int c0 = ck*128;
        __syncthreads();
        if (i < MQ) {
#pragma unroll
            for (int j = 0; j < 8; ++j) {
                int cc = ccb + 4*j;
                int cg = c0 + cc;
                int phys = i*256 + ((((cc>>3) ^ (i&15)))<<4) + ((cc&7)*2);
                s16x4 pv, qv;
                if (cg < MS) {
                    float4 v  = *(const float4*)(sr + cg);
                    float4 r1 = *(const float4*)&r10s[cg];
                    pv.x = (short)f2bf(__expf(10.f*(v.x - 1.0f))*r1.x);
                    pv.y = (short)f2bf(__expf(10.f*(v.y - 1.0f))*r1.y);
                    pv.z = (short)f2bf(__expf(10.f*(v.z - 1.0f))*r1.z);
                    pv.w = (short)f2bf(__expf(10.f*(v.w - 1.0f))*r1.w);
                    qv.x = (short)f2bf(__expf(20.f*(v.x - 1.0f)));
                    qv.y = (short)f2bf(__expf(20.f*(v.y - 1.0f)));
                    qv.z = (short)f2bf(__expf(20.f*(v.z - 1.0f)));
                    qv.w = (short)f2bf(__expf(20.f*(v.w - 1.0f)));
                } else {
                    pv = (s16x4){0,0,0,0}; qv = (s16x4){0,0,0,0};
                }
                *(s16x4*)(PT + phys) = pv;
                *(s16x4*)(QT + phys) = qv;
            }
        } else {
            short one = (short)0x3F80;
#pragma unroll
            for (int j = 0; j < 8; ++j) {
                int cc = ccb + 4*j;
                int cg = c0 + cc;
                int phys = i*256 + ((((cc>>3) ^ (i&15)))<<4) + ((cc&7)*2);
                s16x4 z = (s16x4){0,0,0,0};
                s16x4 ov = z;
                if (i == MQ && cg < MS) ov = (s16x4){one, one, one, one};
                *(s16x4*)(PT + phys) = ov;   // ones-row in P' -> row 100 of B = rowsum(Q_un)
                *(s16x4*)(QT + phys) = ov;   // ones-row in Q  -> col 100 of B = rhs sums
            }
        }
        __syncthreads();
#pragma unroll
        for (int kk = 0; kk < 8; ++kk) {
            int sA = (kk*2 + kg) ^ (grA & 15);
            bf16x8 af = *(const bf16x8*)(PT + grA*256 + (sA<<4));
#pragma unroll
            for (int nt = 0; nt < 2; ++nt) {
                int gc = (ch*2 + nt)*32 + (l & 31);
                int sB = (kk*2 + kg) ^ (gc & 15);
                bf16x8 bfr = *(const bf16x8*)(QT + gc*256 + (sB<<4));
                acc[nt] = __builtin_amdgcn_mfma_f32_32x32x16_bf16(af, bfr, acc[nt], 0, 0, 0);
            }
        }
    }
    __syncthreads();

    float* Bsh = (float*)PQ;          // [101][101] un-normalized B
#pragma unroll
    for (int nt = 0; nt < 2; ++nt) {
        int col = (ch*2 + nt)*32 + (l & 31);
        if (col > MQ) continue;
#pragma unroll
        for (int rg = 0; rg < 16; ++rg) {
            int row = rw*32 + (rg & 3) + 8*(rg >> 2) + 4*(l >> 5);
            if (row <= MQ) Bsh[row*101 + col] = acc[nt][rg];
        }
    }
    __syncthreads();
    if (t < MQ) {
        float r20 = 1.0f / Bsh[100*101 + t];     // rowsum(Q_un)_t from the MFMA
        r20L[t] = r20;
        float r = 1.0f + 0.5f*Bsh[t*101 + 100];  // rhs from ones-col
        rh[t] = r;
        xs[t] = r;
        ys[t] = r20 * r;
    }
    __syncthreads();
    // Jacobi on Bu with y = r20 o x :  x = rh + 0.25 * Bu * y  (10 iters: 0.25^10 ~ 1e-6)
    int jr = t % MQ, jp = t / MQ;     // t<400: (row, part)
    for (int it = 0; it < 10; ++it) {
        if (t < 4*MQ) {
            float s = 0.f;
            const float* br = &Bsh[jr*101 + jp*25];
            const float* yv = &ys[jp*25];
#pragma unroll
            for (int j = 0; j < 25; ++j) s += br[j]*yv[j];
            ps[jp][jr] = s;
        }
        __syncthreads();
        if (t < MQ) {
            float x = rh[t] + 0.25f*(ps[0][t] + ps[1][t] + ps[2][t] + ps[3][t]);
            xs[t] = x;
            ys[t] = r20L[t] * x;
        }
        __syncthreads();
    }
    float kv = (t < MQ) ? (xs[t] - 1.0f) : 0.f;
    if (t < 128) {
        float s = kv;
        for (int off = 32; off; off >>= 1) s += __shfl_xor(s, off);
        if ((t & 63) == 0) partial[t >> 6] = s;
    }
    __syncthreads();
    float tot = partial[0] + partial[1];
    if (t < MQ) out[sys*MQ + t] = kv / tot;
}

extern "C" void kernel_launch(void* const* d_in, const int* in_sizes, int n_in,
                              void* d_out, int out_size, void* d_ws, size_t ws_size,
                              hipStream_t stream) {
    const float* sup = (const float*)d_in[0];
    const float* qry = (const float*)d_in[1];
    float* out = (float*)d_out;
    float* ws  = (float*)d_ws;

    float* supmean = ws;                        // 1,280,000 f (layout keeper)
    float* invs    = supmean + 1280000;         // 2,000 (unused)
    float* invq    = invs + 2000;               // 30,000 (unused)
    float* Smat    = invq + 30000;              // 15,000,000
    float* m20     = Smat + 15000000;           // 30,000 (unused)
    float* rd20    = m20 + 30000;               // 30,000 (unused)
    float* m10     = rd20 + 30000;              // 150,000 (unused)
    float* rd10    = m10 + 150000;              // 150,000 (unused)
    float* Bm      = rd10 + 150000;             // 3,000,000
    float* rh      = Bm + 3000000;              // 30,000 (unused)
    ushort* AhT    = (ushort*)(rh + 30000);     // 20*966,656 = 19,333,120 u16
    ushort* BhT    = AhT + 19333120;            // 20*65,536 = 1,310,720 u16
    float* npq     = Bm;                        // 20 x 30000 = 600,000
    float* nps     = Bm + 600000;               // 20 x 2000  = 40,000

    k_prep_all<<<dim3(NCHK, BATCH*NQ + BATCH*NWAY), 256, 0, stream>>>(
        qry, sup, AhT, BhT, npq, nps);
    k_gemm<<<NWG, 256, 0, stream>>>(AhT, BhT, npq, nps, Smat);
    k_fsolve<<<NSYS, 512, 0, stream>>>(Smat, out);
}

// Round 28
// 106.228 us; speedup vs baseline: 1.1178x; 1.0389x over previous
//
#include <hip/hip_runtime.h>
#include <math.h>

#define BATCH 4
#define NSUP 25
#define NQ   75
#define CH   640
#define HW   100
#define NWAY 5
#define KSHOT 5
#define NSYS (BATCH*NQ)   // 300
#define MS   (NWAY*HW)    // 500
#define MQ   HW           // 100
#define MTOT (NQ*HW)      // 7500 rows per batch
#define NCHK 20           // c-chunks of 32

// chunk-major slab geometry (u16 units)
#define A_BSTRIDE 241664          // 7552*32 (59 slabs of 128 rows)
#define A_KSTRIDE 966656          // 4*A_BSTRIDE
#define B_BSTRIDE 16384           // 512*32  (4 slabs)
#define B_KSTRIDE 65536           // 4*B_BSTRIDE

typedef __attribute__((ext_vector_type(8))) _Float16 f16x8;
typedef __attribute__((ext_vector_type(8))) short bf16x8;
typedef __attribute__((ext_vector_type(4))) float f32x4;
typedef __attribute__((ext_vector_type(16))) float f32x16;
typedef __attribute__((ext_vector_type(4))) short s16x4;

__device__ __forceinline__ ushort f2bf(float f) {
    unsigned u = __float_as_uint(f);
    u += 0x7fff + ((u >> 16) & 1);          // RNE
    return (ushort)(u >> 16);
}
__device__ __forceinline__ ushort f2h(float f) {
    _Float16 h = (_Float16)f;               // v_cvt_f16_f32, RNE
    return __builtin_bit_cast(unsigned short, h);
}

#define GLD_LDS16(gp, lp) __builtin_amdgcn_global_load_lds( \
    (const __attribute__((address_space(1))) unsigned*)(const void*)(gp), \
    (__attribute__((address_space(3))) unsigned*)(void*)(lp), 16, 0, 0)

// ---------------- K1: transpose + fp16 quantize -> chunk-major pre-swizzled slabs ----------------
__global__ __launch_bounds__(256) void k_prep_all(
        const float* __restrict__ qry, const float* __restrict__ sup,
        ushort* __restrict__ AhT, ushort* __restrict__ BhT,
        float* __restrict__ npq, float* __restrict__ nps) {
    __shared__ float tile[32][101];
    int kt = blockIdx.x;
    int c0 = kt * 32;
    int z  = blockIdx.y;
    int t  = threadIdx.x;
    bool isq = (z < BATCH*NQ);

    ushort* dst; float* normpart; int planesHW; size_t cbase; int brow; int p;
    if (isq) {
        p = z;
        int b = p / NQ, qq = p % NQ;
        dst = AhT; normpart = npq; planesHW = NSYS*HW;
        cbase = (size_t)kt*A_KSTRIDE + (size_t)b*A_BSTRIDE;
        brow = qq*100;
        const float* ib = qry + (size_t)p*CH*HW + (size_t)c0*HW;
#pragma unroll
        for (int ii = 0; ii < 4; ++ii) {
            int idx = ii*256 + t;
            if (idx < 800) {
                int cl = idx / 25, qd = idx % 25;
                float4 v = *(const float4*)(ib + idx*4);
                tile[cl][qd*4+0] = v.x; tile[cl][qd*4+1] = v.y;
                tile[cl][qd*4+2] = v.z; tile[cl][qd*4+3] = v.w;
            }
        }
    } else {
        p = z - BATCH*NQ;
        int b = p / NWAY, n = p % NWAY;
        dst = BhT; normpart = nps; planesHW = BATCH*NWAY*HW;
        cbase = (size_t)kt*B_KSTRIDE + (size_t)b*B_BSTRIDE;
        brow = n*100;
        const float* ib = sup + ((size_t)(b*NSUP + n*KSHOT))*CH*HW + (size_t)c0*HW;
#pragma unroll
        for (int ii = 0; ii < 4; ++ii) {
            int idx = ii*256 + t;
            if (idx < 800) {
                float4 a = {0.f,0.f,0.f,0.f};
#pragma unroll
                for (int k = 0; k < KSHOT; ++k) {
                    float4 w = *(const float4*)(ib + (size_t)k*CH*HW + idx*4);
                    a.x += w.x; a.y += w.y; a.z += w.z; a.w += w.w;
                }
                int cl = idx / 25, qd = idx % 25;
                tile[cl][qd*4+0] = a.x*0.2f; tile[cl][qd*4+1] = a.y*0.2f;
                tile[cl][qd*4+2] = a.z*0.2f; tile[cl][qd*4+3] = a.w*0.2f;
            }
        }
    }
    __syncthreads();
#pragma unroll
    for (int ii = 0; ii < 2; ++ii) {
        int idx = ii*256 + t;
        if (idx < 400) {
            int m  = idx >> 2;
            int sp = idx & 3;
            int rib = brow + m;
            int rl = rib & 127;
            int slab = rib >> 7;
            int cb = ((sp ^ ((rl >> 1) & 3))) << 3;
            bf16x8 o; float ss = 0.f;
#pragma unroll
            for (int j = 0; j < 8; ++j) {
                float f = tile[cb+j][m];
                ss += f*f;
                o[j] = (short)f2h(f);
            }
            size_t off = cbase + (size_t)slab*4096
                       + (size_t)((rl>>1)*64 + (rl&1)*32 + sp*8);
            *(bf16x8*)(dst + off) = o;
            ss += __shfl_xor(ss, 1);
            ss += __shfl_xor(ss, 2);
            if ((t & 3) == 0)
                normpart[(size_t)kt*planesHW + p*HW + m] = ss;
        }
    }
}

// ---------------- K2: fp16 MFMA GEMM, BK=64 double-buffer + counted vmcnt ----------------
#define BM 128
#define BN 128
#define BK 64
#define NKT (CH/BK)           // 10
#define NCT 4
#define NRT 59
#define NWG (NCT*NRT*BATCH)   // 944, divisible by 8
__global__ __launch_bounds__(256) void k_gemm(
        const ushort* __restrict__ AhT, const ushort* __restrict__ BhT,
        const float* __restrict__ npq, const float* __restrict__ nps,
        float* __restrict__ S) {
    __shared__ __align__(1024) char lds[65536];   // 2 x 32KB
    __shared__ float invqL[128], invsL[128];
    int hwid = blockIdx.x;
    int l = (hwid & 7) * (NWG/8) + (hwid >> 3);   // chunked XCD swizzle
    int ct = l & 3;
    int rest = l >> 2;
    int rt = rest % NRT;
    int b  = rest / NRT;
    int t  = threadIdx.x;
    int lane = t & 63, w = t >> 6;
    int row0 = rt * BM, col0 = ct * BN;

    if (t < 128) {
        int gr = row0 + t; if (gr > MTOT-1) gr = MTOT-1;
        float s = 0.f;
#pragma unroll
        for (int u = 0; u < NCHK; ++u) s += npq[(size_t)u*(NSYS*HW) + b*MTOT + gr];
        invqL[t] = 1.0f / (1e-16f + sqrtf(s));
    } else {
        int c = col0 + (t - 128); if (c > MS-1) c = MS-1;
        float s = 0.f;
#pragma unroll
        for (int u = 0; u < NCHK; ++u) s += nps[(size_t)u*(BATCH*NWAY*HW) + b*MS + c];
        invsL[t-128] = 1.0f / (1e-16f + sqrtf(s));
    }

    const ushort* srcA = AhT + (size_t)b*A_BSTRIDE + (size_t)rt*4096;
    const ushort* srcB = BhT + (size_t)b*B_BSTRIDE + (size_t)ct*4096;
    int dA = w << 10;

    f32x4 acc[4][4];
#pragma unroll
    for (int mi = 0; mi < 4; ++mi)
#pragma unroll
        for (int ni = 0; ni < 4; ++ni) acc[mi][ni] = (f32x4){0.f,0.f,0.f,0.f};

    int wr = w >> 1, wc = w & 1;
    int q = lane & 15, kg = lane >> 4;

#define STAGE(bufb, kt_) do { \
        const ushort* pa0 = srcA + (size_t)(2*(kt_))*A_KSTRIDE; \
        const ushort* pa1 = pa0 + A_KSTRIDE; \
        const ushort* pb0 = srcB + (size_t)(2*(kt_))*B_KSTRIDE; \
        const ushort* pb1 = pb0 + B_KSTRIDE; \
        char* bb = lds + (bufb)*32768; \
        GLD_LDS16(pa0 + t*8,        bb + 0     + dA); \
        GLD_LDS16(pa0 + 2048 + t*8, bb + 4096  + dA); \
        GLD_LDS16(pa1 + t*8,        bb + 8192  + dA); \
        GLD_LDS16(pa1 + 2048 + t*8, bb + 12288 + dA); \
        GLD_LDS16(pb0 + t*8,        bb + 16384 + dA); \
        GLD_LDS16(pb0 + 2048 + t*8, bb + 20480 + dA); \
        GLD_LDS16(pb1 + t*8,        bb + 24576 + dA); \
        GLD_LDS16(pb1 + 2048 + t*8, bb + 28672 + dA); \
    } while (0)

    STAGE(0, 0);
    for (int kt = 0; kt < NKT; ++kt) {
        int cur = kt & 1;
        if (kt + 1 < NKT) {
            STAGE(cur ^ 1, kt + 1);
            asm volatile("s_waitcnt vmcnt(8)" ::: "memory");
        } else {
            asm volatile("s_waitcnt vmcnt(0)" ::: "memory");
        }
        __builtin_amdgcn_sched_barrier(0);
        __builtin_amdgcn_s_barrier();
        __builtin_amdgcn_sched_barrier(0);

        const char* buf = lds + cur*32768;
#pragma unroll
        for (int h = 0; h < 2; ++h) {
            const char* Ab = buf + h*8192;
            const char* Bb = buf + 16384 + h*8192;
            f16x8 bf[4];
#pragma unroll
            for (int ni = 0; ni < 4; ++ni) {
                int c = wc*64 + ni*16 + q;
                int off = (c>>1)*128 + (c&1)*64 + ((kg ^ ((c>>1)&3)) << 4);
                bf[ni] = *(const f16x8*)(Bb + off);
            }
#pragma unroll
            for (int mi = 0; mi < 4; ++mi) {
                int r = wr*64 + mi*16 + q;
                int off = (r>>1)*128 + (r&1)*64 + ((kg ^ ((r>>1)&3)) << 4);
                f16x8 af = *(const f16x8*)(Ab + off);
#pragma unroll
                for (int ni = 0; ni < 4; ++ni)
                    acc[mi][ni] = __builtin_amdgcn_mfma_f32_16x16x32_f16(af, bf[ni], acc[mi][ni], 0, 0, 0);
            }
        }
        __builtin_amdgcn_sched_barrier(0);
        __builtin_amdgcn_s_barrier();
        __builtin_amdgcn_sched_barrier(0);
    }
#undef STAGE

    int colb = col0 + wc*64 + q;
    int rowb = row0 + wr*64 + (kg << 2);
#pragma unroll
    for (int mi = 0; mi < 4; ++mi) {
#pragma unroll
        for (int ni = 0; ni < 4; ++ni) {
            int c = colb + ni*16;
            if (c >= MS) continue;
            float si = invsL[c - col0];
#pragma unroll
            for (int j = 0; j < 4; ++j) {
                int r = rowb + mi*16 + j;
                if (r < MTOT)
                    S[((size_t)b*MTOT + r)*MS + c] = acc[mi][ni][j] * invqL[r - row0] * si;
            }
        }
    }
}

// ---------------- K3: fused colsum + MFMA formB + Jacobi, max-free softmax ----------------
__global__ __launch_bounds__(512) void k_fsolve(const float* __restrict__ S,
        float* __restrict__ out) {
    __shared__ __align__(16) char PQ[65536];        // phaseA tmp / PT,QT / Bsh alias
    __shared__ __align__(16) float r10s[MS];
    __shared__ float r20L[MQ];
    __shared__ float xs[MQ], ys[MQ], rh[MQ];
    __shared__ float ps[4][MQ];
    __shared__ float partial[2];
    int sys = blockIdx.x;
    int t = threadIdx.x;
    int l = t & 63, w = t >> 6;
    const float* Sb = S + (size_t)sys*MQ*MS;
    char* PT = PQ;
    char* QT = PQ + 32768;

    // ---- phase A: colsum_c = sum_i exp(10*(S[i][c]-1)) ; r10 = 1/colsum ----
    {
        float (*wcs)[512] = (float(*)[512])PQ;            // [8][512] partials
        float cols[8];
#pragma unroll
        for (int u = 0; u < 8; ++u) cols[u] = 0.f;
        int nu = (l < MS - 448) ? 8 : 7;   // l<52 -> 8 cols
        for (int row = w; row < MQ; row += 8) {
            const float* rp = Sb + (size_t)row*MS;
#pragma unroll
            for (int u = 0; u < 8; ++u)
                if (u < nu) cols[u] += __expf(10.f*(rp[l + 64*u] - 1.0f));
        }
#pragma unroll
        for (int u = 0; u < 8; ++u) wcs[w][l+64*u] = cols[u];
        __syncthreads();
        if (t < MS) {
            float s = 0.f;
#pragma unroll
            for (int w2 = 0; w2 < 8; ++w2) s += wcs[w2][t];
            r10s[t] = 1.0f/s;
        }
        // barrier provided by first ck-iteration's __syncthreads()
    }

    int i = t >> 2;                  // 0..127, row per 4 threads
    int ccb = (t & 3) * 32;          // 32-col slice

    f32x16 acc[2];
#pragma unroll
    for (int nt = 0; nt < 2; ++nt)
#pragma unroll
        for (int rg = 0; rg < 16; ++rg) acc[nt][rg] = 0.f;

    int rw = w & 3, ch = w >> 2;
    int grA = rw*32 + (l & 31);
    int kg = l >> 5;
    const float* sr = Sb + (size_t)i*MS;

    for (int ck = 0; ck < 4; ++ck) {
        int c0 = ck*128;
        __syncthreads();
        if (i < MQ) {
#pragma unroll
            for (int j = 0; j < 8; ++j) {
                int cc = ccb + 4*j;
                int cg = c0 + cc;
                int phys = i*256 + ((((cc>>3) ^ (i&15)))<<4) + ((cc&7)*2);
                s16x4 pv, qv;
                if (cg < MS) {
                    float4 v  = *(const float4*)(sr + cg);
                    float4 r1 = *(const float4*)&r10s[cg];
                    float ex = __expf(10.f*(v.x - 1.0f));
                    float ey = __expf(10.f*(v.y - 1.0f));
                    float ez = __expf(10.f*(v.z - 1.0f));
                    float ew = __expf(10.f*(v.w - 1.0f));
                    pv.x = (short)f2bf(ex*r1.x);
                    pv.y = (short)f2bf(ey*r1.y);
                    pv.z = (short)f2bf(ez*r1.z);
                    pv.w = (short)f2bf(ew*r1.w);
                    qv.x = (short)f2bf(ex*ex);      // e20 = e10^2
                    qv.y = (short)f2bf(ey*ey);
                    qv.z = (short)f2bf(ez*ez);
                    qv.w = (short)f2bf(ew*ew);
                } else {
                    pv = (s16x4){0,0,0,0}; qv = (s16x4){0,0,0,0};
                }
                *(s16x4*)(PT + phys) = pv;
                *(s16x4*)(QT + phys) = qv;
            }
        } else {
            short one = (short)0x3F80;
#pragma unroll
            for (int j = 0; j < 8; ++j) {
                int cc = ccb + 4*j;
                int cg = c0 + cc;
                int phys = i*256 + ((((cc>>3) ^ (i&15)))<<4) + ((cc&7)*2);
                s16x4 z = (s16x4){0,0,0,0};
                s16x4 ov = z;
                if (i == MQ && cg < MS) ov = (s16x4){one, one, one, one};
                *(s16x4*)(PT + phys) = ov;   // ones-row in P' -> row 100 of B = rowsum(Q_un)
                *(s16x4*)(QT + phys) = ov;   // ones-row in Q  -> col 100 of B = rhs sums
            }
        }
        __syncthreads();
#pragma unroll
        for (int kk = 0; kk < 8; ++kk) {
            int sA = (kk*2 + kg) ^ (grA & 15);
            bf16x8 af = *(const bf16x8*)(PT + grA*256 + (sA<<4));
#pragma unroll
            for (int nt = 0; nt < 2; ++nt) {
                int gc = (ch*2 + nt)*32 + (l & 31);
                int sB = (kk*2 + kg) ^ (gc & 15);
                bf16x8 bfr = *(const bf16x8*)(QT + gc*256 + (sB<<4));
                acc[nt] = __builtin_amdgcn_mfma_f32_32x32x16_bf16(af, bfr, acc[nt], 0, 0, 0);
            }
        }
    }
    __syncthreads();

    float* Bsh = (float*)PQ;          // [101][101] un-normalized B
#pragma unroll
    for (int nt = 0; nt < 2; ++nt) {
        int col = (ch*2 + nt)*32 + (l & 31);
        if (col > MQ) continue;
#pragma unroll
        for (int rg = 0; rg < 16; ++rg) {
            int row = rw*32 + (rg & 3) + 8*(rg >> 2) + 4*(l >> 5);
            if (row <= MQ) Bsh[row*101 + col] = acc[nt][rg];
        }
    }
    __syncthreads();
    if (t < MQ) {
        float r20 = 1.0f / Bsh[100*101 + t];     // rowsum(Q_un)_t from the MFMA
        r20L[t] = r20;
        float r = 1.0f + 0.5f*Bsh[t*101 + 100];  // rhs from ones-col
        rh[t] = r;
        xs[t] = r;
        ys[t] = r20 * r;
    }
    __syncthreads();
    // Jacobi on Bu with y = r20 o x :  x = rh + 0.25 * Bu * y  (8 iters: 0.25^8 ~ 1.5e-5)
    int jr = t % MQ, jp = t / MQ;     // t<400: (row, part)
    for (int it = 0; it < 8; ++it) {
        if (t < 4*MQ) {
            float s = 0.f;
            const float* br = &Bsh[jr*101 + jp*25];
            const float* yv = &ys[jp*25];
#pragma unroll
            for (int j = 0; j < 25; ++j) s += br[j]*yv[j];
            ps[jp][jr] = s;
        }
        __syncthreads();
        if (t < MQ) {
            float x = rh[t] + 0.25f*(ps[0][t] + ps[1][t] + ps[2][t] + ps[3][t]);
            xs[t] = x;
            ys[t] = r20L[t] * x;
        }
        __syncthreads();
    }
    float kv = (t < MQ) ? (xs[t] - 1.0f) : 0.f;
    if (t < 128) {
        float s = kv;
        for (int off = 32; off; off >>= 1) s += __shfl_xor(s, off);
        if ((t & 63) == 0) partial[t >> 6] = s;
    }
    __syncthreads();
    float tot = partial[0] + partial[1];
    if (t < MQ) out[sys*MQ + t] = kv / tot;
}

extern "C" void kernel_launch(void* const* d_in, const int* in_sizes, int n_in,
                              void* d_out, int out_size, void* d_ws, size_t ws_size,
                              hipStream_t stream) {
    const float* sup = (const float*)d_in[0];
    const float* qry = (const float*)d_in[1];
    float* out = (float*)d_out;
    float* ws  = (float*)d_ws;

    float* supmean = ws;                        // 1,280,000 f (layout keeper)
    float* invs    = supmean + 1280000;         // 2,000 (unused)
    float* invq    = invs + 2000;               // 30,000 (unused)
    float* Smat    = invq + 30000;              // 15,000,000
    float* m20     = Smat + 15000000;           // 30,000 (unused)
    float* rd20    = m20 + 30000;               // 30,000 (unused)
    float* m10     = rd20 + 30000;              // 150,000 (unused)
    float* rd10    = m10 + 150000;              // 150,000 (unused)
    float* Bm      = rd10 + 150000;             // 3,000,000
    float* rh      = Bm + 3000000;              // 30,000 (unused)
    ushort* AhT    = (ushort*)(rh + 30000);     // 20*966,656 = 19,333,120 u16
    ushort* BhT    = AhT + 19333120;            // 20*65,536 = 1,310,720 u16
    float* npq     = Bm;                        // 20 x 30000 = 600,000
    float* nps     = Bm + 600000;               // 20 x 2000  = 40,000

    k_prep_all<<<dim3(NCHK, BATCH*NQ + BATCH*NWAY), 256, 0, stream>>>(
        qry, sup, AhT, BhT, npq, nps);
    k_gemm<<<NWG, 256, 0, stream>>>(AhT, BhT, npq, nps, Smat);
    k_fsolve<<<NSYS, 512, 0, stream>>>(Smat, out);
}